// Round 9
// baseline (20.008 us; speedup 1.0000x reference)
//
#include <hip/hip_runtime.h>
#include <math.h>

#define LL 50
#define DD 50
#define RR 3
#define CC 10
#define SPB 32          // samples per block in kernel 2
#define K1_BLOCKS 512   // kernel 1 grid (grid-stride over vocab rows)

// ---------------- Kernel 1: dtab[v] = (row_v.w0, row_v.w1, row_v.w2, 0) ----
// 4 lanes per vocab row, grid-stride. Lane q handles float2-pairs [s, s+c):
// q0:0..6, q1:7..12, q2:13..18, q3:19..24. W staged in LDS.
__global__ __launch_bounds__(256) void precompute_dots_kernel(
    const float* __restrict__ emb_table,  // [VOCAB, D]
    const float* __restrict__ W,          // [150]
    float4*      __restrict__ dtab,       // [VOCAB]
    int vocab)
{
    __shared__ float sW[RR * DD];
    if (threadIdx.x < RR * DD) sW[threadIdx.x] = W[threadIdx.x];
    __syncthreads();

    const int tid    = blockIdx.x * 256 + threadIdx.x;
    const int q      = tid & 3;                    // quarter within row group
    const int s      = 6 * q + (q > 0 ? 1 : 0);    // 0,7,13,19
    const int c      = (q == 0) ? 7 : 6;
    const int stride = (K1_BLOCKS * 256) >> 2;     // rows per sweep = 32768

    for (int r = tid >> 2; r < vocab; r += stride) {
        const float2* p = reinterpret_cast<const float2*>(emb_table + (size_t)r * DD);
        float d0 = 0.f, d1 = 0.f, d2 = 0.f;
        #pragma unroll
        for (int k = 0; k < 7; ++k) {
            if (k < c) {
                float2 e = p[s + k];
                int j = 2 * (s + k);
                d0 = fmaf(e.x, sW[          j], fmaf(e.y, sW[          j + 1], d0));
                d1 = fmaf(e.x, sW[    DD  + j], fmaf(e.y, sW[    DD  + j + 1], d1));
                d2 = fmaf(e.x, sW[2 * DD  + j], fmaf(e.y, sW[2 * DD  + j + 1], d2));
            }
        }
        // Reduce across the 4-lane group (stays inside the group).
        d0 += __shfl_xor(d0, 1); d0 += __shfl_xor(d0, 2);
        d1 += __shfl_xor(d1, 1); d1 += __shfl_xor(d1, 2);
        d2 += __shfl_xor(d2, 1); d2 += __shfl_xor(d2, 2);
        if (q == 0) dtab[r] = make_float4(d0, d1, d2, 0.f);
    }
}

// ---------------- Kernel 2: thread-per-combo + LDS-staged x/mask ----------
// Block = 32 samples. Stage x/mask (32*50 ints + floats, 12.8 KB) with
// coalesced vec4 loads; each 16-lane group evaluates 2 samples (t=0,1):
// combo load, 6 LDS lookups, 3 dtab component gathers (L2-resident 1.6MB),
// sigmoid, 16-lane shfl tree.
__global__ __launch_bounds__(256) void combo_eval_kernel(
    const int*   __restrict__ x,          // [B, L]
    const float* __restrict__ emb_mask,   // [B, L]
    const int*   __restrict__ combo_idx,  // [B, C, R]
    const float* __restrict__ dtabf,      // [VOCAB*4]: component rr at 4*row+rr
    const float* __restrict__ bvec,       // [1]
    float*       __restrict__ out,        // [B]
    int B)
{
    __shared__ int   s_x[SPB * LL];       // 1600 ints
    __shared__ float s_m[SPB * LL];       // 1600 floats

    const int tid = threadIdx.x;
    const int b0  = blockIdx.x * SPB;

    // Stage: 1600 elems = 400 vec4 per array; 256 threads -> 2 iterations.
    // b0*LL*4 bytes = 6400*blockIdx -> 16B-aligned.
    #pragma unroll
    for (int i = tid; i < SPB * LL / 4; i += 256) {
        reinterpret_cast<int4*>(s_x)[i] =
            reinterpret_cast<const int4*>(x + (size_t)b0 * LL)[i];
        reinterpret_cast<float4*>(s_m)[i] =
            reinterpret_cast<const float4*>(emb_mask + (size_t)b0 * LL)[i];
    }
    __syncthreads();

    const int lane = tid & 63;
    const int g    = ((tid >> 6) << 2) + (lane >> 4);   // group 0..15
    const int c    = lane & 15;                          // combo, <10 active
    const float bias = bvec[0];

    #pragma unroll
    for (int t = 0; t < SPB / 16; ++t) {
        const int sid = g + 16 * t;
        const int b   = b0 + sid;
        float v = 0.f;
        if (b < B && c < CC) {
            const int* cp = combo_idx + ((size_t)b * CC + c) * RR;
            int i0 = cp[0];
            int i1 = cp[1];
            int i2 = cp[2];
            const int base = sid * LL;
            int   r0 = s_x[base + i0], r1 = s_x[base + i1], r2 = s_x[base + i2];
            float m0 = s_m[base + i0], m1 = s_m[base + i1], m2 = s_m[base + i2];
            float sacc = dtabf[4 * r0 + 0] * m0
                       + dtabf[4 * r1 + 1] * m1
                       + dtabf[4 * r2 + 2] * m2
                       + bias;
            v = __builtin_amdgcn_rcpf(1.0f + __expf(-sacc));
        }
        // Sum within each 16-lane group (lanes c>=10 carry zeros).
        v += __shfl_down(v, 8);
        v += __shfl_down(v, 4);
        v += __shfl_down(v, 2);
        v += __shfl_down(v, 1);
        if (c == 0 && b < B) out[b] = v;
    }
}

extern "C" void kernel_launch(void* const* d_in, const int* in_sizes, int n_in,
                              void* d_out, int out_size, void* d_ws, size_t ws_size,
                              hipStream_t stream) {
    const int*   x         = (const int*)d_in[0];
    const float* emb_mask  = (const float*)d_in[1];
    const int*   combo_idx = (const int*)d_in[2];
    // d_in[3] = step (unused)
    const float* emb_table = (const float*)d_in[4];
    const float* W         = (const float*)d_in[5];
    const float* bvec      = (const float*)d_in[6];
    float*       out       = (float*)d_out;

    const int B     = out_size;            // OUT == 1
    const int vocab = in_sizes[4] / DD;    // emb_table is [VOCAB, D]

    float4* dtab = (float4*)d_ws;          // 16 * VOCAB = 1.6 MB scratch

    precompute_dots_kernel<<<K1_BLOCKS, 256, 0, stream>>>(
        emb_table, W, dtab, vocab);

    combo_eval_kernel<<<(B + SPB - 1) / SPB, 256, 0, stream>>>(
        x, emb_mask, combo_idx, (const float*)dtab, bvec, out, B);
}